// Round 8
// baseline (395.129 us; speedup 1.0000x reference)
//
#include <hip/hip_runtime.h>
#include <math.h>

// Qwen3.5 TopK Router, MI355X. fp64-accumulated GEMM for exact index ordering.
// logits = X(T,D) @ W(E,D)^T ; softmax over E; top-8 + renormalize.
// Out layout (all fp32): [T*E softmax-probs | T*K weights | T*K indices-as-float]
//
// R8 vs R7 (gemm 239us @ VALUBusy 71% / 2 blocks/CU; epilogue ~50us @ 1 blk/CU):
//  - split-K x NS (NS=4 if ws_size fits 4*T*E*8=67MB, else proven NS=2):
//    grid NS*256 of 256-thread blocks -> 4 independent blocks/CU, 4 waves/SIMD.
//    VALU work unchanged (170us); issue bubbles (29%) shrink. LDS pipe check:
//    16 waves x 3 ds_read_b128 x 12cyc = 576 < VALU 784 cyc/kk-window -> still
//    VALU-bound. launch_bounds(256,4) caps VGPR at 128 (R7 used 80 -> no spill).
//  - epilogue: 1024 blocks x 16 tokens (1 token per ty-group) = 4 blocks/CU;
//    ~77MB traffic -> ~20us instead of 50.
//  - A: phi-swizzle k-major (stores 2-way free). B: interleaved
//    pos(e)=(e&3)+4*(e>>3)+64*((e>>2)&1), psi(k)=((k>>2)&3)<<2 (reads free,
//    stores 4-way cheap; measured 3.1e6 conflict cycles in R7).
//  - NS-term sequential fp64 partial sum: error ~1e-13, index order safe.

constexpr int T = 16384;
constexpr int D = 2048;
constexpr int E = 128;
constexpr int K = 8;

constexpr int BM = 64;    // tokens per gemm block
constexpr int BK = 32;    // k-chunk

template <int NS>
__global__ __launch_bounds__(256, 4)
void router_gemm(const float* __restrict__ X,
                 const float* __restrict__ W,
                 double* __restrict__ ws)
{
    constexpr int KG = D / NS;

    __shared__ float As[BK * BM];   // [k][tok ^ phi(k)]      8 KB
    __shared__ float Bs[BK * E];    // [k][pos(e) ^ psi(k)]  16 KB

    const int tid = threadIdx.x;
    const int g   = blockIdx.x & (NS - 1);      // k-slice
    const long t0 = (long)(blockIdx.x / NS) * BM;
    const int tx  = tid & 15;                   // expert group (8 experts)
    const int ty  = tid >> 4;                   // token group (4 tokens)

    double acc[4][8];
#pragma unroll
    for (int i = 0; i < 4; ++i)
#pragma unroll
        for (int j = 0; j < 8; ++j) acc[i][j] = 0.0;

    const int ar = tid >> 3;            // 0..31
    const int ac = (tid & 7) << 2;      // 0,4,...,28
    const int phiS = ((ac >> 2) & 3) << 3;   // A-store token XOR
    const int psiS = ((ac >> 2) & 3) << 2;   // B-store pos XOR

    const float* Xp = X + (t0 + ar) * D + (long)g * KG + ac;
    const float* Wp = W + (long)ar * D + (long)g * KG + ac;

    // prologue: tile 0
    float4 a0 = *(const float4*)(Xp);
    float4 a1 = *(const float4*)(Xp + 32L * D);
    float4 b0 = *(const float4*)(Wp);
    float4 b1 = *(const float4*)(Wp + 32L * D);
    float4 b2 = *(const float4*)(Wp + 64L * D);
    float4 b3 = *(const float4*)(Wp + 96L * D);

    for (int k0 = 0; k0 < KG; k0 += BK) {
        __syncthreads();   // previous tile fully consumed
        {
            const int cA0 = ar ^ phiS, cA1 = (ar + 32) ^ phiS;
            As[(ac+0)*BM + cA0] = a0.x; As[(ac+1)*BM + cA0] = a0.y;
            As[(ac+2)*BM + cA0] = a0.z; As[(ac+3)*BM + cA0] = a0.w;
            As[(ac+0)*BM + cA1] = a1.x; As[(ac+1)*BM + cA1] = a1.y;
            As[(ac+2)*BM + cA1] = a1.z; As[(ac+3)*BM + cA1] = a1.w;

            const int e0 = ar, e1 = ar + 32, e2 = ar + 64, e3 = ar + 96;
            const int p0 = ((e0&3) + ((e0>>3)<<2) + (((e0>>2)&1)<<6)) ^ psiS;
            const int p1 = ((e1&3) + ((e1>>3)<<2) + (((e1>>2)&1)<<6)) ^ psiS;
            const int p2 = ((e2&3) + ((e2>>3)<<2) + (((e2>>2)&1)<<6)) ^ psiS;
            const int p3 = ((e3&3) + ((e3>>3)<<2) + (((e3>>2)&1)<<6)) ^ psiS;
            Bs[(ac+0)*E + p0] = b0.x; Bs[(ac+1)*E + p0] = b0.y;
            Bs[(ac+2)*E + p0] = b0.z; Bs[(ac+3)*E + p0] = b0.w;
            Bs[(ac+0)*E + p1] = b1.x; Bs[(ac+1)*E + p1] = b1.y;
            Bs[(ac+2)*E + p1] = b1.z; Bs[(ac+3)*E + p1] = b1.w;
            Bs[(ac+0)*E + p2] = b2.x; Bs[(ac+1)*E + p2] = b2.y;
            Bs[(ac+2)*E + p2] = b2.z; Bs[(ac+3)*E + p2] = b2.w;
            Bs[(ac+0)*E + p3] = b3.x; Bs[(ac+1)*E + p3] = b3.y;
            Bs[(ac+2)*E + p3] = b3.z; Bs[(ac+3)*E + p3] = b3.w;
        }
        __syncthreads();

        // prefetch next tile while computing this one
        const int kn = k0 + BK;
        if (kn < KG) {
            a0 = *(const float4*)(Xp + kn);
            a1 = *(const float4*)(Xp + kn + 32L * D);
            b0 = *(const float4*)(Wp + kn);
            b1 = *(const float4*)(Wp + kn + 32L * D);
            b2 = *(const float4*)(Wp + kn + 64L * D);
            b3 = *(const float4*)(Wp + kn + 96L * D);
        }

#pragma unroll
        for (int kk = 0; kk < BK; ++kk) {
            const int phi = ((kk >> 2) & 3) << 3;
            const int psi = ((kk >> 2) & 3) << 2;
            const int bb  = (tx << 2) ^ psi;   // experts 8tx..8tx+3 ; +64 -> +4..+7
            float4 av  = *(const float4*)&As[kk*BM + ((ty << 2) ^ phi)];
            float4 bv0 = *(const float4*)&Bs[kk*E + bb];
            float4 bv1 = *(const float4*)&Bs[kk*E + bb + 64];
            const double a[4] = {(double)av.x, (double)av.y, (double)av.z, (double)av.w};
            const double b[8] = {(double)bv0.x, (double)bv0.y, (double)bv0.z, (double)bv0.w,
                                 (double)bv1.x, (double)bv1.y, (double)bv1.z, (double)bv1.w};
#pragma unroll
            for (int i = 0; i < 4; ++i)
#pragma unroll
                for (int j = 0; j < 8; ++j)
                    acc[i][j] = fma(a[i], b[j], acc[i][j]);
        }
    }

    // write fp64 partials: ws[g][t][e]
#pragma unroll
    for (int i = 0; i < 4; ++i) {
        const long t = t0 + (ty << 2) + i;
        double* dst = ws + ((long)g * T + t) * E + (tx << 3);
        *(double2*)(dst + 0) = make_double2(acc[i][0], acc[i][1]);
        *(double2*)(dst + 2) = make_double2(acc[i][2], acc[i][3]);
        *(double2*)(dst + 4) = make_double2(acc[i][4], acc[i][5]);
        *(double2*)(dst + 6) = make_double2(acc[i][6], acc[i][7]);
    }
}

template <int NS>
__global__ __launch_bounds__(256, 4)
void router_epilogue(const double* __restrict__ ws,
                     float* __restrict__ out)
{
    const int tid = threadIdx.x;
    const int tx  = tid & 15;
    const int ty  = tid >> 4;
    const long t  = (long)blockIdx.x * 16 + ty;   // one token per ty-group

    double acc[8];
    {
        const double* s = ws + t * E + (tx << 3);
#pragma unroll
        for (int h = 0; h < 4; ++h) {
            double2 u = *(const double2*)(s + 2*h);
            acc[2*h+0] = u.x;
            acc[2*h+1] = u.y;
        }
#pragma unroll
        for (int g = 1; g < NS; ++g) {
            const double* sg = s + (long)g * T * E;
#pragma unroll
            for (int h = 0; h < 4; ++h) {
                double2 u = *(const double2*)(sg + 2*h);
                acc[2*h+0] += u.x;
                acc[2*h+1] += u.y;
            }
        }
    }

    float* outL  = out;
    float* outWt = out + (long)T * E;
    float* outId = outWt + (long)T * K;

    double m = acc[0];
#pragma unroll
    for (int j = 1; j < 8; ++j) m = fmax(m, acc[j]);
#pragma unroll
    for (int mask = 1; mask <= 8; mask <<= 1)
        m = fmax(m, __shfl_xor(m, mask, 64));

    float e[8]; float s = 0.f;
#pragma unroll
    for (int j = 0; j < 8; ++j) { e[j] = __expf((float)(acc[j] - m)); s += e[j]; }
#pragma unroll
    for (int mask = 1; mask <= 8; mask <<= 1)
        s += __shfl_xor(s, mask, 64);
    const float inv = 1.f / s;

    float p[8];
#pragma unroll
    for (int j = 0; j < 8; ++j) p[j] = e[j] * inv;

    float4 st0 = {p[0], p[1], p[2], p[3]};
    float4 st1 = {p[4], p[5], p[6], p[7]};
    *(float4*)&outL[t * E + (tx << 3)]     = st0;
    *(float4*)&outL[t * E + (tx << 3) + 4] = st1;

    // top-8 on fp64 LOGITS (value desc, index asc) == jax.lax.top_k order
    double v[8];
#pragma unroll
    for (int j = 0; j < 8; ++j) v[j] = acc[j];

    float pk[K]; int ik[K]; float tsum = 0.f;
#pragma unroll
    for (int r = 0; r < K; ++r) {
        double bv = -1.0e300; int bi = 0x7fffffff;
#pragma unroll
        for (int j = 0; j < 8; ++j) {
            const int idx = (tx << 3) + j;
            const bool better = (v[j] > bv) || (v[j] == bv && idx < bi);
            bv = better ? v[j] : bv;
            bi = better ? idx : bi;
        }
#pragma unroll
        for (int mask = 1; mask <= 8; mask <<= 1) {
            const double ov = __shfl_xor(bv, mask, 64);
            const int    oi = __shfl_xor(bi, mask, 64);
            const bool better = (ov > bv) || (ov == bv && oi < bi);
            bv = better ? ov : bv;
            bi = better ? oi : bi;
        }
        const float pw = __expf((float)(bv - m)) * inv;
        pk[r] = pw; ik[r] = bi; tsum += pw;
        if ((bi >> 3) == tx) v[bi & 7] = -1.0e300;
    }

    if (tx == 0) {
        const float rinv = 1.f / tsum;
#pragma unroll
        for (int r = 0; r < K; ++r) {
            outWt[t * K + r] = pk[r] * rinv;
            outId[t * K + r] = (float)ik[r];
        }
    }
}

extern "C" void kernel_launch(void* const* d_in, const int* in_sizes, int n_in,
                              void* d_out, int out_size, void* d_ws, size_t ws_size,
                              hipStream_t stream)
{
    const float* X = (const float*)d_in[0];
    const float* W = (const float*)d_in[1];
    float* out = (float*)d_out;
    double* ws = (double*)d_ws;

    const size_t need4 = 4UL * T * E * sizeof(double);   // 67.1 MB
    if (ws_size >= need4) {
        router_gemm<4><<<dim3(4 * (T / BM)), dim3(256), 0, stream>>>(X, W, ws);
        router_epilogue<4><<<dim3(T / 16), dim3(256), 0, stream>>>(ws, out);
    } else {
        router_gemm<2><<<dim3(2 * (T / BM)), dim3(256), 0, stream>>>(X, W, ws);
        router_epilogue<2><<<dim3(T / 16), dim3(256), 0, stream>>>(ws, out);
    }
}

// Round 10
// 368.369 us; speedup vs baseline: 1.0726x; 1.0726x over previous
//
#include <hip/hip_runtime.h>
#include <math.h>

// Qwen3.5 TopK Router, MI355X. fp64-accumulated GEMM for exact index ordering.
// logits = X(T,D) @ W(E,D)^T ; softmax over E; top-8 + renormalize.
// Out layout (all fp32): [T*E softmax-probs | T*K weights | T*K indices-as-float]
//
// R10 = R7's PROVEN gemm (launch_bounds(256,2), VGPR 80, no spill) with
// split-K x4 grid + R8's parallel epilogue. Key lesson from R8: the
// regression there was launch_bounds(256,4) (allocator shrank to 64 arch
// VGPRs -> fp64 acc spilled, +24MB scratch), NOT the NS=4 split. With
// (256,2) bounds residency = min(grid 4/CU, LDS 6/CU, VGPR ~6/CU) = 4
// independent blocks/CU -> barrier/LDS bubbles (29% at 2 blocks/CU in R7)
// shrink while VALU work is unchanged.
// R9's f64-MFMA attempt is abandoned: probs passed / indices failed ->
// ~0.01-0.05-scale logit errors from an unverifiable f64 fragment-layout
// detail; not iterating blindly on it.

constexpr int T = 16384;
constexpr int D = 2048;
constexpr int E = 128;
constexpr int K = 8;

constexpr int BM = 64;    // tokens per gemm block
constexpr int BK = 32;    // k-chunk

template <int NS>
__global__ __launch_bounds__(256, 2)
void router_gemm(const float* __restrict__ X,
                 const float* __restrict__ W,
                 double* __restrict__ ws)
{
    constexpr int KG = D / NS;

    __shared__ float As[BK * BM];   // [k][tok ^ phi(k)]      8 KB
    __shared__ float Bs[BK * E];    // [k][pos(e) ^ psi(k)]  16 KB

    const int tid = threadIdx.x;
    const int g   = blockIdx.x & (NS - 1);      // k-slice
    const long t0 = (long)(blockIdx.x / NS) * BM;
    const int tx  = tid & 15;                   // expert group (8 experts)
    const int ty  = tid >> 4;                   // token group (4 tokens)

    double acc[4][8];
#pragma unroll
    for (int i = 0; i < 4; ++i)
#pragma unroll
        for (int j = 0; j < 8; ++j) acc[i][j] = 0.0;

    const int ar = tid >> 3;            // 0..31
    const int ac = (tid & 7) << 2;      // 0,4,...,28
    const int phiS = ((ac >> 2) & 3) << 3;   // A-store token XOR
    const int psiS = ((ac >> 2) & 3) << 2;   // B-store pos XOR

    const float* Xp = X + (t0 + ar) * D + (long)g * KG + ac;
    const float* Wp = W + (long)ar * D + (long)g * KG + ac;

    // prologue: tile 0
    float4 a0 = *(const float4*)(Xp);
    float4 a1 = *(const float4*)(Xp + 32L * D);
    float4 b0 = *(const float4*)(Wp);
    float4 b1 = *(const float4*)(Wp + 32L * D);
    float4 b2 = *(const float4*)(Wp + 64L * D);
    float4 b3 = *(const float4*)(Wp + 96L * D);

    for (int k0 = 0; k0 < KG; k0 += BK) {
        __syncthreads();   // previous tile fully consumed
        {
            const int cA0 = ar ^ phiS, cA1 = (ar + 32) ^ phiS;
            As[(ac+0)*BM + cA0] = a0.x; As[(ac+1)*BM + cA0] = a0.y;
            As[(ac+2)*BM + cA0] = a0.z; As[(ac+3)*BM + cA0] = a0.w;
            As[(ac+0)*BM + cA1] = a1.x; As[(ac+1)*BM + cA1] = a1.y;
            As[(ac+2)*BM + cA1] = a1.z; As[(ac+3)*BM + cA1] = a1.w;

            const int e0 = ar, e1 = ar + 32, e2 = ar + 64, e3 = ar + 96;
            const int p0 = ((e0&3) + ((e0>>3)<<2) + (((e0>>2)&1)<<6)) ^ psiS;
            const int p1 = ((e1&3) + ((e1>>3)<<2) + (((e1>>2)&1)<<6)) ^ psiS;
            const int p2 = ((e2&3) + ((e2>>3)<<2) + (((e2>>2)&1)<<6)) ^ psiS;
            const int p3 = ((e3&3) + ((e3>>3)<<2) + (((e3>>2)&1)<<6)) ^ psiS;
            Bs[(ac+0)*E + p0] = b0.x; Bs[(ac+1)*E + p0] = b0.y;
            Bs[(ac+2)*E + p0] = b0.z; Bs[(ac+3)*E + p0] = b0.w;
            Bs[(ac+0)*E + p1] = b1.x; Bs[(ac+1)*E + p1] = b1.y;
            Bs[(ac+2)*E + p1] = b1.z; Bs[(ac+3)*E + p1] = b1.w;
            Bs[(ac+0)*E + p2] = b2.x; Bs[(ac+1)*E + p2] = b2.y;
            Bs[(ac+2)*E + p2] = b2.z; Bs[(ac+3)*E + p2] = b2.w;
            Bs[(ac+0)*E + p3] = b3.x; Bs[(ac+1)*E + p3] = b3.y;
            Bs[(ac+2)*E + p3] = b3.z; Bs[(ac+3)*E + p3] = b3.w;
        }
        __syncthreads();

        // prefetch next tile while computing this one
        const int kn = k0 + BK;
        if (kn < KG) {
            a0 = *(const float4*)(Xp + kn);
            a1 = *(const float4*)(Xp + kn + 32L * D);
            b0 = *(const float4*)(Wp + kn);
            b1 = *(const float4*)(Wp + kn + 32L * D);
            b2 = *(const float4*)(Wp + kn + 64L * D);
            b3 = *(const float4*)(Wp + kn + 96L * D);
        }

#pragma unroll
        for (int kk = 0; kk < BK; ++kk) {
            const int phi = ((kk >> 2) & 3) << 3;
            const int psi = ((kk >> 2) & 3) << 2;
            const int bb  = (tx << 2) ^ psi;   // experts 8tx..8tx+3 ; +64 -> +4..+7
            float4 av  = *(const float4*)&As[kk*BM + ((ty << 2) ^ phi)];
            float4 bv0 = *(const float4*)&Bs[kk*E + bb];
            float4 bv1 = *(const float4*)&Bs[kk*E + bb + 64];
            const double a[4] = {(double)av.x, (double)av.y, (double)av.z, (double)av.w};
            const double b[8] = {(double)bv0.x, (double)bv0.y, (double)bv0.z, (double)bv0.w,
                                 (double)bv1.x, (double)bv1.y, (double)bv1.z, (double)bv1.w};
#pragma unroll
            for (int i = 0; i < 4; ++i)
#pragma unroll
                for (int j = 0; j < 8; ++j)
                    acc[i][j] = fma(a[i], b[j], acc[i][j]);
        }
    }

    // write fp64 partials: ws[g][t][e]
#pragma unroll
    for (int i = 0; i < 4; ++i) {
        const long t = t0 + (ty << 2) + i;
        double* dst = ws + ((long)g * T + t) * E + (tx << 3);
        *(double2*)(dst + 0) = make_double2(acc[i][0], acc[i][1]);
        *(double2*)(dst + 2) = make_double2(acc[i][2], acc[i][3]);
        *(double2*)(dst + 4) = make_double2(acc[i][4], acc[i][5]);
        *(double2*)(dst + 6) = make_double2(acc[i][6], acc[i][7]);
    }
}

template <int NS>
__global__ __launch_bounds__(256, 4)
void router_epilogue(const double* __restrict__ ws,
                     float* __restrict__ out)
{
    const int tid = threadIdx.x;
    const int tx  = tid & 15;
    const int ty  = tid >> 4;
    const long t  = (long)blockIdx.x * 16 + ty;   // one token per ty-group

    double acc[8];
    {
        const double* s = ws + t * E + (tx << 3);
#pragma unroll
        for (int h = 0; h < 4; ++h) {
            double2 u = *(const double2*)(s + 2*h);
            acc[2*h+0] = u.x;
            acc[2*h+1] = u.y;
        }
#pragma unroll
        for (int g = 1; g < NS; ++g) {
            const double* sg = s + (long)g * T * E;
#pragma unroll
            for (int h = 0; h < 4; ++h) {
                double2 u = *(const double2*)(sg + 2*h);
                acc[2*h+0] += u.x;
                acc[2*h+1] += u.y;
            }
        }
    }

    float* outL  = out;
    float* outWt = out + (long)T * E;
    float* outId = outWt + (long)T * K;

    double m = acc[0];
#pragma unroll
    for (int j = 1; j < 8; ++j) m = fmax(m, acc[j]);
#pragma unroll
    for (int mask = 1; mask <= 8; mask <<= 1)
        m = fmax(m, __shfl_xor(m, mask, 64));

    float e[8]; float s = 0.f;
#pragma unroll
    for (int j = 0; j < 8; ++j) { e[j] = __expf((float)(acc[j] - m)); s += e[j]; }
#pragma unroll
    for (int mask = 1; mask <= 8; mask <<= 1)
        s += __shfl_xor(s, mask, 64);
    const float inv = 1.f / s;

    float p[8];
#pragma unroll
    for (int j = 0; j < 8; ++j) p[j] = e[j] * inv;

    float4 st0 = {p[0], p[1], p[2], p[3]};
    float4 st1 = {p[4], p[5], p[6], p[7]};
    *(float4*)&outL[t * E + (tx << 3)]     = st0;
    *(float4*)&outL[t * E + (tx << 3) + 4] = st1;

    // top-8 on fp64 LOGITS (value desc, index asc) == jax.lax.top_k order
    double v[8];
#pragma unroll
    for (int j = 0; j < 8; ++j) v[j] = acc[j];

    float pk[K]; int ik[K]; float tsum = 0.f;
#pragma unroll
    for (int r = 0; r < K; ++r) {
        double bv = -1.0e300; int bi = 0x7fffffff;
#pragma unroll
        for (int j = 0; j < 8; ++j) {
            const int idx = (tx << 3) + j;
            const bool better = (v[j] > bv) || (v[j] == bv && idx < bi);
            bv = better ? v[j] : bv;
            bi = better ? idx : bi;
        }
#pragma unroll
        for (int mask = 1; mask <= 8; mask <<= 1) {
            const double ov = __shfl_xor(bv, mask, 64);
            const int    oi = __shfl_xor(bi, mask, 64);
            const bool better = (ov > bv) || (ov == bv && oi < bi);
            bv = better ? ov : bv;
            bi = better ? oi : bi;
        }
        const float pw = __expf((float)(bv - m)) * inv;
        pk[r] = pw; ik[r] = bi; tsum += pw;
        if ((bi >> 3) == tx) v[bi & 7] = -1.0e300;
    }

    if (tx == 0) {
        const float rinv = 1.f / tsum;
#pragma unroll
        for (int r = 0; r < K; ++r) {
            outWt[t * K + r] = pk[r] * rinv;
            outId[t * K + r] = (float)ik[r];
        }
    }
}

extern "C" void kernel_launch(void* const* d_in, const int* in_sizes, int n_in,
                              void* d_out, int out_size, void* d_ws, size_t ws_size,
                              hipStream_t stream)
{
    const float* X = (const float*)d_in[0];
    const float* W = (const float*)d_in[1];
    float* out = (float*)d_out;
    double* ws = (double*)d_ws;

    const size_t need4 = 4UL * T * E * sizeof(double);   // 67.1 MB
    if (ws_size >= need4) {
        router_gemm<4><<<dim3(4 * (T / BM)), dim3(256), 0, stream>>>(X, W, ws);
        router_epilogue<4><<<dim3(T / 16), dim3(256), 0, stream>>>(ws, out);
    } else {
        router_gemm<2><<<dim3(2 * (T / BM)), dim3(256), 0, stream>>>(X, W, ws);
        router_epilogue<2><<<dim3(T / 16), dim3(256), 0, stream>>>(ws, out);
    }
}